// Round 18
// baseline (31.159 us; speedup 1.0000x reference)
//
#include <hip/hip_runtime.h>

// VectorQuantizer via MX-scaled fp8 MFMA (32x32x64, unit scales).
// R18: K-SPLIT — 2 waves per block, each wave scans HALF the codebook
// (16 tiles) for the same 32 rows; packed-key cross-wave merge via a 256B
// LDS table (u32 min preserves exact jnp.argmin first-min semantics since
// the global code id is embedded in the key). Halves each wave's serial
// hot-loop chain while keeping R16's full-unroll load hoisting (lower
// register pressure than R16's 32-tile body).
// x staged through LDS (R15 win); hot loop fully unrolled (R16 win).
// Prep stores E'' = fp8(-1024*e) in exact per-lane fragment order: tile t
// (32 codes x 64 dims, 2 KB) so lane l reads its 32-byte B operand as two
// contiguous 1KB-coalesced b128 loads. acc = mfma(x8, E'', C=512)
// = 512*(1-2x.e) > 0 (positive scale preserves packed-key order; ||e||^2
// <= 6.1e-5 dropped — below key resolution; any argmin flip bounded
// elementwise by 2/1024 = 0.00195 << 0.025 threshold).
// out[0..N*D) = x + (q-x), out[N*D] = 1.25*mean((q-x)^2)  (exact fp32).

typedef __attribute__((ext_vector_type(8)))  int   i32x8;
typedef __attribute__((ext_vector_type(16))) float f32x16;

constexpr int N_ROWS = 256 * 512;   // 131072
constexpr int D      = 64;
constexpr int K      = 1024;
constexpr int TPB    = 128;                      // 2 waves per block
constexpr int RPB    = 32;                       // rows per block (one tile)
constexpr int NBLK   = N_ROWS / RPB;             // 4096
constexpr int NT     = K / 32;                   // 32 code tiles
constexpr int TPW    = NT / 2;                   // 16 tiles per wave
constexpr int LROW   = 68;                       // LDS floats/row (272 B pad)

// ---- prep: E -> fp8(-1024*e) in fragment order --------------------------
// Tile t = codes [32t, 32t+32), 2 KB: main-loop lane l reads slot s at
// uint4 index t*128 + s*64 + l, giving k = (l>>5)*32 + s*16 + [0..16).
__global__ __launch_bounds__(64) void vq_prep_kernel(
    const float* __restrict__ emb, uint4* __restrict__ ebf) {
  int c = blockIdx.x * 64 + threadIdx.x;   // 16 blocks x 64 threads
  if (c >= K) return;
  const float* e = emb + (size_t)c * D;
  const int t = c >> 5, col = c & 31;
  const float sc = -1024.f;
#pragma unroll
  for (int kh = 0; kh < 2; ++kh) {
#pragma unroll
    for (int s = 0; s < 2; ++s) {
      const float* p = e + kh * 32 + s * 16;   // 16 dims
      uint4 slot;
      unsigned* dw = (unsigned*)&slot;
#pragma unroll
      for (int d = 0; d < 4; ++d) {
        float4 f = *(const float4*)(p + d * 4);
        int v = 0;
        v = __builtin_amdgcn_cvt_pk_fp8_f32(sc * f.x, sc * f.y, v, false);
        v = __builtin_amdgcn_cvt_pk_fp8_f32(sc * f.z, sc * f.w, v, true);
        dw[d] = (unsigned)v;
      }
      ebf[t * 128 + s * 64 + col + 32 * kh] = slot;
    }
  }
}

// ---------------------------------------------------------------- main -----
__global__ __launch_bounds__(TPB, 3) void vq_main_kernel(
    const float* __restrict__ x, const uint4* __restrict__ ebf,
    const float* __restrict__ emb, float* __restrict__ out,
    float* __restrict__ partial) {
  __shared__ float    s_x[RPB * LROW];   // 8.5 KB staged x rows
  __shared__ unsigned s_key[RPB][2];     // 256 B  per-wave candidate keys
  __shared__ float    s_w[2];

  const int tid  = threadIdx.x;
  const int wave = tid >> 6, lane = tid & 63;
  const int col  = lane & 31;   // A row / B col / C col
  const int kh   = lane >> 5;   // k-half (32 dims each)
  const int rig  = lane >> 4;   // row-in-group for coalesced phases
  const int chk  = lane & 15;   // float4 chunk in row

  const size_t rbase = (size_t)blockIdx.x * RPB;

  // Coalesced x stage: both waves together, 4 insts x 2 KB contiguous.
#pragma unroll
  for (int g = 0; g < 4; ++g) {
    const int row = g * 8 + (tid >> 4);
    float4 v = ((const float4*)(x + (rbase + row) * D))[tid & 15];
    *(float4*)&s_x[row * LROW + (tid & 15) * 4] = v;
  }
  __syncthreads();   // all 32 rows visible to both waves

  // A fragment: lane holds row col, k = kh*32 + [0..32) as 32 fp8 bytes.
  i32x8 xa;
#pragma unroll
  for (int d = 0; d < 8; ++d) {
    float4 f = *(const float4*)&s_x[col * LROW + kh * 32 + d * 4];
    int v = 0;
    v = __builtin_amdgcn_cvt_pk_fp8_f32(f.x, f.y, v, false);
    v = __builtin_amdgcn_cvt_pk_fp8_f32(f.z, f.w, v, true);
    xa[d] = v;
  }

  unsigned kmin[16];
#pragma unroll
  for (int j = 0; j < 16; ++j) kmin[j] = 0xFFFFFFFFu;

  f32x16 c512;
#pragma unroll
  for (int j = 0; j < 16; ++j) c512[j] = 512.f;   // C-in: 512*(1-2x.e) > 0

  // Hot loop, fully unrolled, HALF the codebook per wave (16 tiles).
  const uint4* eb_base = ebf + (size_t)wave * TPW * 128;
#pragma unroll
  for (int tt = 0; tt < TPW; ++tt) {
    uint4 ev0 = eb_base[tt * 128 + lane];        // k bytes  0..15
    uint4 ev1 = eb_base[tt * 128 + 64 + lane];   // k bytes 16..31
    i32x8 eb;
    eb[0] = (int)ev0.x; eb[1] = (int)ev0.y; eb[2] = (int)ev0.z; eb[3] = (int)ev0.w;
    eb[4] = (int)ev1.x; eb[5] = (int)ev1.y; eb[6] = (int)ev1.z; eb[7] = (int)ev1.w;
    const unsigned code = (unsigned)((wave * TPW + tt) * 32 + col);
    f32x16 acc = __builtin_amdgcn_mfma_scale_f32_32x32x64_f8f6f4(
        xa, eb, c512, 0, 0, 0, 0x7F7F7F7F, 0, 0x7F7F7F7F);
#pragma unroll
    for (int j = 0; j < 16; ++j) {   // acc[j] == 512*(dist+1) > 0
      unsigned key = (__builtin_bit_cast(unsigned, acc[j]) & 0xFFFFFC00u) |
                     code;
      kmin[j] = kmin[j] < key ? kmin[j] : key;
    }
  }

  // Cross-col argmin: 32 cols of each row live in one 32-lane half.
#pragma unroll
  for (int m = 1; m <= 16; m <<= 1) {
#pragma unroll
    for (int j = 0; j < 16; ++j) {
      unsigned o = (unsigned)__shfl_xor((int)kmin[j], m, 64);
      kmin[j] = kmin[j] < o ? kmin[j] : o;
    }
  }

  // Publish full keys: C/D row = (j&3) + 8*(j>>2) + 4*kh.
  if (col == 0) {
#pragma unroll
    for (int j = 0; j < 16; ++j)
      s_key[(j & 3) + 8 * (j >> 2) + 4 * kh][wave] = kmin[j];
  }
  __syncthreads();   // both waves' candidates visible

  // Epilogue: wave w owns rows [16w, 16w+16). Cross-wave merge = 1 min.
  float lp = 0.f;
#pragma unroll
  for (int g = 0; g < 4; ++g) {
    const int wrow = wave * 16 + g * 4 + rig;
    const size_t r = rbase + wrow;
    unsigned k0 = s_key[wrow][0], k1 = s_key[wrow][1];
    const int bi = (int)((k0 < k1 ? k0 : k1) & 1023u);
    float4 xv = *(const float4*)&s_x[wrow * LROW + chk * 4];
    float4 qv = ((const float4*)(emb + (size_t)bi * D))[chk];
    float dx = qv.x - xv.x, dy = qv.y - xv.y;
    float dz = qv.z - xv.z, dw = qv.w - xv.w;
    lp = fmaf(dx, dx, lp); lp = fmaf(dy, dy, lp);
    lp = fmaf(dz, dz, lp); lp = fmaf(dw, dw, lp);
    float4 ov;
    ov.x = xv.x + dx; ov.y = xv.y + dy;   // same rounding as x + sg(q-x)
    ov.z = xv.z + dz; ov.w = xv.w + dw;
    ((float4*)(out + r * D))[chk] = ov;
  }

#pragma unroll
  for (int o2 = 32; o2 > 0; o2 >>= 1) lp += __shfl_down(lp, o2, 64);
  if (lane == 0) s_w[wave] = lp;
  __syncthreads();
  if (tid == 0) partial[blockIdx.x] = s_w[0] + s_w[1];
}

// ---------------------------------------------------------------- loss -----
__global__ __launch_bounds__(256) void vq_loss_kernel(
    const float* __restrict__ partial, float* __restrict__ out) {
  __shared__ float wsum[4];
  int tid = threadIdx.x;
  float v = 0.f;
#pragma unroll
  for (int i = 0; i < NBLK / 256; ++i) v += partial[tid + i * 256];
#pragma unroll
  for (int off = 32; off > 0; off >>= 1) v += __shfl_down(v, off, 64);
  if ((tid & 63) == 0) wsum[tid >> 6] = v;
  __syncthreads();
  if (tid == 0) {
    float total = (wsum[0] + wsum[1]) + (wsum[2] + wsum[3]);
    out[(size_t)N_ROWS * D] = 1.25f * total / (float)((size_t)N_ROWS * D);
  }
}

// ------------------------------------------------------------- launch ------
extern "C" void kernel_launch(void* const* d_in, const int* in_sizes, int n_in,
                              void* d_out, int out_size, void* d_ws,
                              size_t ws_size, hipStream_t stream) {
  const float* x   = (const float*)d_in[0];   // [131072, 64] fp32
  const float* emb = (const float*)d_in[1];   // [1024, 64] fp32
  float* out = (float*)d_out;

  char* ws = (char*)d_ws;
  float* partial = (float*)ws;                 // 16 KB (NBLK floats)
  uint4* ebf     = (uint4*)(ws + 16384);       // 64 KB fp8 codebook

  vq_prep_kernel<<<16, 64, 0, stream>>>(emb, ebf);
  vq_main_kernel<<<NBLK, TPB, 0, stream>>>(x, ebf, emb, out, partial);
  vq_loss_kernel<<<1, 256, 0, stream>>>(partial, out);
}

// Round 19
// 29.840 us; speedup vs baseline: 1.0442x; 1.0442x over previous
//
#include <hip/hip_runtime.h>

// VectorQuantizer via MX-scaled fp8 MFMA (32x32x64, unit scales), 1-wave
// blocks, NO barriers. x staged through LDS (R15 win: kills strided-gather
// TA cost). Hot loop FULLY unrolled + launch_bounds(64,3) (~170 VGPR) so
// the compiler hoists E-tile L2 loads deep enough to cover their ~200cyc
// latency (R16 win). [R17 pairing/min3 and R18 K-split both regressed;
// this is the measured-best structure, restored verbatim.]
// Prep stores E'' = fp8(-1024*e) in exact per-lane fragment order: tile t
// (32 codes x 64 dims, 2 KB) so lane l reads its 32-byte B operand as two
// contiguous 1KB-coalesced b128 loads. acc = mfma(x8, E'', C=512)
// = 512*(1-2x.e) > 0 (positive scale preserves packed-key order; ||e||^2
// <= 6.1e-5 dropped — below key resolution; any argmin flip bounded
// elementwise by 2/1024 = 0.00195 << 0.025 threshold).
// argmin via packed u32 keys (bits high 22 | code 10) -> 5-step shfl min
// per 32-lane col group -> col==0 lanes publish row minima to s_bi
// (same-wave write/read: lgkmcnt ordering, no barrier).
// out[0..N*D) = x + (q-x), out[N*D] = 1.25*mean((q-x)^2)  (exact fp32).

typedef __attribute__((ext_vector_type(8)))  int   i32x8;
typedef __attribute__((ext_vector_type(16))) float f32x16;

constexpr int N_ROWS = 256 * 512;   // 131072
constexpr int D      = 64;
constexpr int K      = 1024;
constexpr int TPB    = 64;                       // ONE wave per block
constexpr int RPW    = 32;                       // rows per wave (one tile)
constexpr int NBLK   = N_ROWS / RPW;             // 4096
constexpr int NT     = K / 32;                   // 32 code tiles
constexpr int LROW   = 68;                       // LDS floats/row (272 B pad)

// ---- prep: E -> fp8(-1024*e) in fragment order --------------------------
// Tile t = codes [32t, 32t+32), 2 KB: main-loop lane l reads slot s at
// uint4 index t*128 + s*64 + l, giving k = (l>>5)*32 + s*16 + [0..16).
__global__ __launch_bounds__(64) void vq_prep_kernel(
    const float* __restrict__ emb, uint4* __restrict__ ebf) {
  int c = blockIdx.x * 64 + threadIdx.x;   // 16 blocks x 64 threads
  if (c >= K) return;
  const float* e = emb + (size_t)c * D;
  const int t = c >> 5, col = c & 31;
  const float sc = -1024.f;
#pragma unroll
  for (int kh = 0; kh < 2; ++kh) {
#pragma unroll
    for (int s = 0; s < 2; ++s) {
      const float* p = e + kh * 32 + s * 16;   // 16 dims
      uint4 slot;
      unsigned* dw = (unsigned*)&slot;
#pragma unroll
      for (int d = 0; d < 4; ++d) {
        float4 f = *(const float4*)(p + d * 4);
        int v = 0;
        v = __builtin_amdgcn_cvt_pk_fp8_f32(sc * f.x, sc * f.y, v, false);
        v = __builtin_amdgcn_cvt_pk_fp8_f32(sc * f.z, sc * f.w, v, true);
        dw[d] = (unsigned)v;
      }
      ebf[t * 128 + s * 64 + col + 32 * kh] = slot;
    }
  }
}

// ---------------------------------------------------------------- main -----
__global__ __launch_bounds__(TPB, 3) void vq_main_kernel(
    const float* __restrict__ x, const uint4* __restrict__ ebf,
    const float* __restrict__ emb, float* __restrict__ out,
    float* __restrict__ partial) {
  __shared__ float s_x[RPW * LROW];   // 8.5 KB staged x rows
  __shared__ int   s_bi[RPW];         // 128 B; same-wave write/read only

  const int lane = threadIdx.x;
  const int col  = lane & 31;   // A row / B col / C col
  const int kh   = lane >> 5;   // k-half (32 dims each)
  const int rig  = lane >> 4;   // row-in-group for coalesced phases
  const int chk  = lane & 15;   // float4 chunk in row

  const size_t rbase = (size_t)blockIdx.x * RPW;

  // Coalesced x stage: 8 insts x 1 KB contiguous (rows 4g..4g+3).
#pragma unroll
  for (int g = 0; g < 8; ++g) {
    const int row = g * 4 + rig;
    float4 v = ((const float4*)(x + (rbase + row) * D))[chk];
    *(float4*)&s_x[row * LROW + chk * 4] = v;
  }

  // A fragment from LDS (same wave wrote it -> lgkmcnt ordering):
  // lane holds row col, k = kh*32 + [0..32) as 32 fp8 bytes.
  i32x8 xa;
#pragma unroll
  for (int d = 0; d < 8; ++d) {
    float4 f = *(const float4*)&s_x[col * LROW + kh * 32 + d * 4];
    int v = 0;
    v = __builtin_amdgcn_cvt_pk_fp8_f32(f.x, f.y, v, false);
    v = __builtin_amdgcn_cvt_pk_fp8_f32(f.z, f.w, v, true);
    xa[d] = v;
  }

  unsigned kmin[16];
#pragma unroll
  for (int j = 0; j < 16; ++j) kmin[j] = 0xFFFFFFFFu;

  f32x16 c512;
#pragma unroll
  for (int j = 0; j < 16; ++j) c512[j] = 512.f;   // C-in: 512*(1-2x.e) > 0

  // Hot loop, FULLY unrolled: straight-line code -> compiler hoists the
  // 2 coalesced b128 L2 loads of each tile deep ahead of their MFMA.
#pragma unroll
  for (int t = 0; t < NT; ++t) {
    uint4 ev0 = ebf[t * 128 + lane];        // k bytes  0..15 of this lane
    uint4 ev1 = ebf[t * 128 + 64 + lane];   // k bytes 16..31
    i32x8 eb;
    eb[0] = (int)ev0.x; eb[1] = (int)ev0.y; eb[2] = (int)ev0.z; eb[3] = (int)ev0.w;
    eb[4] = (int)ev1.x; eb[5] = (int)ev1.y; eb[6] = (int)ev1.z; eb[7] = (int)ev1.w;
    const unsigned code = (unsigned)(t * 32 + col);
    f32x16 acc = __builtin_amdgcn_mfma_scale_f32_32x32x64_f8f6f4(
        xa, eb, c512, 0, 0, 0, 0x7F7F7F7F, 0, 0x7F7F7F7F);
#pragma unroll
    for (int j = 0; j < 16; ++j) {   // acc[j] == 512*(dist+1) > 0
      unsigned key = (__builtin_bit_cast(unsigned, acc[j]) & 0xFFFFFC00u) |
                     code;
      kmin[j] = kmin[j] < key ? kmin[j] : key;
    }
  }

  // Cross-col argmin: 32 cols of each row live in one 32-lane half.
#pragma unroll
  for (int m = 1; m <= 16; m <<= 1) {
#pragma unroll
    for (int j = 0; j < 16; ++j) {
      unsigned o = (unsigned)__shfl_xor((int)kmin[j], m, 64);
      kmin[j] = kmin[j] < o ? kmin[j] : o;
    }
  }

  // Publish: C/D row = (j&3) + 8*(j>>2) + 4*kh. col==0 lanes (0 and 32)
  // hold all 16 row-minima of their half.
  if (col == 0) {
#pragma unroll
    for (int j = 0; j < 16; ++j)
      s_bi[(j & 3) + 8 * (j >> 2) + 4 * kh] = (int)(kmin[j] & 1023u);
  }

  // Epilogue (same-wave lgkmcnt ordering): x from LDS, emb gather from L2,
  // 1 KB contiguous out stores.
  float lp = 0.f;
#pragma unroll
  for (int g = 0; g < RPW / 4; ++g) {
    const int wrow = g * 4 + rig;
    const size_t r = rbase + wrow;
    const int bi = s_bi[wrow];
    float4 xv = *(const float4*)&s_x[wrow * LROW + chk * 4];
    float4 qv = ((const float4*)(emb + (size_t)bi * D))[chk];
    float dx = qv.x - xv.x, dy = qv.y - xv.y;
    float dz = qv.z - xv.z, dw = qv.w - xv.w;
    lp = fmaf(dx, dx, lp); lp = fmaf(dy, dy, lp);
    lp = fmaf(dz, dz, lp); lp = fmaf(dw, dw, lp);
    float4 ov;
    ov.x = xv.x + dx; ov.y = xv.y + dy;   // same rounding as x + sg(q-x)
    ov.z = xv.z + dz; ov.w = xv.w + dw;
    ((float4*)(out + r * D))[chk] = ov;
  }

#pragma unroll
  for (int o2 = 32; o2 > 0; o2 >>= 1) lp += __shfl_down(lp, o2, 64);
  if (lane == 0) partial[blockIdx.x] = lp;
}

// ---------------------------------------------------------------- loss -----
__global__ __launch_bounds__(256) void vq_loss_kernel(
    const float* __restrict__ partial, float* __restrict__ out) {
  __shared__ float wsum[4];
  int tid = threadIdx.x;
  float v = 0.f;
#pragma unroll
  for (int i = 0; i < NBLK / 256; ++i) v += partial[tid + i * 256];
#pragma unroll
  for (int off = 32; off > 0; off >>= 1) v += __shfl_down(v, off, 64);
  if ((tid & 63) == 0) wsum[tid >> 6] = v;
  __syncthreads();
  if (tid == 0) {
    float total = (wsum[0] + wsum[1]) + (wsum[2] + wsum[3]);
    out[(size_t)N_ROWS * D] = 1.25f * total / (float)((size_t)N_ROWS * D);
  }
}

// ------------------------------------------------------------- launch ------
extern "C" void kernel_launch(void* const* d_in, const int* in_sizes, int n_in,
                              void* d_out, int out_size, void* d_ws,
                              size_t ws_size, hipStream_t stream) {
  const float* x   = (const float*)d_in[0];   // [131072, 64] fp32
  const float* emb = (const float*)d_in[1];   // [1024, 64] fp32
  float* out = (float*)d_out;

  char* ws = (char*)d_ws;
  float* partial = (float*)ws;                 // 16 KB (NBLK floats)
  uint4* ebf     = (uint4*)(ws + 16384);       // 64 KB fp8 codebook

  vq_prep_kernel<<<16, 64, 0, stream>>>(emb, ebf);
  vq_main_kernel<<<NBLK, TPB, 0, stream>>>(x, ebf, emb, out, partial);
  vq_loss_kernel<<<1, 256, 0, stream>>>(partial, out);
}

// Round 20
// 29.707 us; speedup vs baseline: 1.0489x; 1.0045x over previous
//
#include <hip/hip_runtime.h>

// VectorQuantizer via MX-scaled fp8 MFMA (32x32x64, unit scales), 1-wave
// blocks, NO barriers. x staged through LDS (R15 win: kills strided-gather
// TA cost). Hot loop FULLY unrolled (R16 win: deep E-load hoisting).
// R20: launch_bounds(64,2) — 256-VGPR cap, 2 waves/SIMD — one more step in
// the proven hoist-depth-over-occupancy direction (R15->R16 trend; R10/R13
// showed occupancy is non-binding in this latency-bound regime).
// Prep stores E'' = fp8(-1024*e) in exact per-lane fragment order: tile t
// (32 codes x 64 dims, 2 KB) so lane l reads its 32-byte B operand as two
// contiguous 1KB-coalesced b128 loads. acc = mfma(x8, E'', C=512)
// = 512*(1-2x.e) > 0 (positive scale preserves packed-key order; ||e||^2
// <= 6.1e-5 dropped — below key resolution; any argmin flip bounded
// elementwise by 2/1024 = 0.00195 << 0.025 threshold).
// argmin via packed u32 keys (bits high 22 | code 10) -> 5-step shfl min
// per 32-lane col group -> col==0 lanes publish row minima to s_bi
// (same-wave write/read: lgkmcnt ordering, no barrier).
// out[0..N*D) = x + (q-x), out[N*D] = 1.25*mean((q-x)^2)  (exact fp32).

typedef __attribute__((ext_vector_type(8)))  int   i32x8;
typedef __attribute__((ext_vector_type(16))) float f32x16;

constexpr int N_ROWS = 256 * 512;   // 131072
constexpr int D      = 64;
constexpr int K      = 1024;
constexpr int TPB    = 64;                       // ONE wave per block
constexpr int RPW    = 32;                       // rows per wave (one tile)
constexpr int NBLK   = N_ROWS / RPW;             // 4096
constexpr int NT     = K / 32;                   // 32 code tiles
constexpr int LROW   = 68;                       // LDS floats/row (272 B pad)

// ---- prep: E -> fp8(-1024*e) in fragment order --------------------------
// Tile t = codes [32t, 32t+32), 2 KB: main-loop lane l reads slot s at
// uint4 index t*128 + s*64 + l, giving k = (l>>5)*32 + s*16 + [0..16).
__global__ __launch_bounds__(64) void vq_prep_kernel(
    const float* __restrict__ emb, uint4* __restrict__ ebf) {
  int c = blockIdx.x * 64 + threadIdx.x;   // 16 blocks x 64 threads
  if (c >= K) return;
  const float* e = emb + (size_t)c * D;
  const int t = c >> 5, col = c & 31;
  const float sc = -1024.f;
#pragma unroll
  for (int kh = 0; kh < 2; ++kh) {
#pragma unroll
    for (int s = 0; s < 2; ++s) {
      const float* p = e + kh * 32 + s * 16;   // 16 dims
      uint4 slot;
      unsigned* dw = (unsigned*)&slot;
#pragma unroll
      for (int d = 0; d < 4; ++d) {
        float4 f = *(const float4*)(p + d * 4);
        int v = 0;
        v = __builtin_amdgcn_cvt_pk_fp8_f32(sc * f.x, sc * f.y, v, false);
        v = __builtin_amdgcn_cvt_pk_fp8_f32(sc * f.z, sc * f.w, v, true);
        dw[d] = (unsigned)v;
      }
      ebf[t * 128 + s * 64 + col + 32 * kh] = slot;
    }
  }
}

// ---------------------------------------------------------------- main -----
__global__ __launch_bounds__(TPB, 2) void vq_main_kernel(
    const float* __restrict__ x, const uint4* __restrict__ ebf,
    const float* __restrict__ emb, float* __restrict__ out,
    float* __restrict__ partial) {
  __shared__ float s_x[RPW * LROW];   // 8.5 KB staged x rows
  __shared__ int   s_bi[RPW];         // 128 B; same-wave write/read only

  const int lane = threadIdx.x;
  const int col  = lane & 31;   // A row / B col / C col
  const int kh   = lane >> 5;   // k-half (32 dims each)
  const int rig  = lane >> 4;   // row-in-group for coalesced phases
  const int chk  = lane & 15;   // float4 chunk in row

  const size_t rbase = (size_t)blockIdx.x * RPW;

  // Coalesced x stage: 8 insts x 1 KB contiguous (rows 4g..4g+3).
#pragma unroll
  for (int g = 0; g < 8; ++g) {
    const int row = g * 4 + rig;
    float4 v = ((const float4*)(x + (rbase + row) * D))[chk];
    *(float4*)&s_x[row * LROW + chk * 4] = v;
  }

  // A fragment from LDS (same wave wrote it -> lgkmcnt ordering):
  // lane holds row col, k = kh*32 + [0..32) as 32 fp8 bytes.
  i32x8 xa;
#pragma unroll
  for (int d = 0; d < 8; ++d) {
    float4 f = *(const float4*)&s_x[col * LROW + kh * 32 + d * 4];
    int v = 0;
    v = __builtin_amdgcn_cvt_pk_fp8_f32(f.x, f.y, v, false);
    v = __builtin_amdgcn_cvt_pk_fp8_f32(f.z, f.w, v, true);
    xa[d] = v;
  }

  unsigned kmin[16];
#pragma unroll
  for (int j = 0; j < 16; ++j) kmin[j] = 0xFFFFFFFFu;

  f32x16 c512;
#pragma unroll
  for (int j = 0; j < 16; ++j) c512[j] = 512.f;   // C-in: 512*(1-2x.e) > 0

  // Hot loop, FULLY unrolled: straight-line code + 256-VGPR budget ->
  // compiler hoists the 2 coalesced b128 L2 loads of each tile ~2x deeper.
#pragma unroll
  for (int t = 0; t < NT; ++t) {
    uint4 ev0 = ebf[t * 128 + lane];        // k bytes  0..15 of this lane
    uint4 ev1 = ebf[t * 128 + 64 + lane];   // k bytes 16..31
    i32x8 eb;
    eb[0] = (int)ev0.x; eb[1] = (int)ev0.y; eb[2] = (int)ev0.z; eb[3] = (int)ev0.w;
    eb[4] = (int)ev1.x; eb[5] = (int)ev1.y; eb[6] = (int)ev1.z; eb[7] = (int)ev1.w;
    const unsigned code = (unsigned)(t * 32 + col);
    f32x16 acc = __builtin_amdgcn_mfma_scale_f32_32x32x64_f8f6f4(
        xa, eb, c512, 0, 0, 0, 0x7F7F7F7F, 0, 0x7F7F7F7F);
#pragma unroll
    for (int j = 0; j < 16; ++j) {   // acc[j] == 512*(dist+1) > 0
      unsigned key = (__builtin_bit_cast(unsigned, acc[j]) & 0xFFFFFC00u) |
                     code;
      kmin[j] = kmin[j] < key ? kmin[j] : key;
    }
  }

  // Cross-col argmin: 32 cols of each row live in one 32-lane half.
#pragma unroll
  for (int m = 1; m <= 16; m <<= 1) {
#pragma unroll
    for (int j = 0; j < 16; ++j) {
      unsigned o = (unsigned)__shfl_xor((int)kmin[j], m, 64);
      kmin[j] = kmin[j] < o ? kmin[j] : o;
    }
  }

  // Publish: C/D row = (j&3) + 8*(j>>2) + 4*kh. col==0 lanes (0 and 32)
  // hold all 16 row-minima of their half.
  if (col == 0) {
#pragma unroll
    for (int j = 0; j < 16; ++j)
      s_bi[(j & 3) + 8 * (j >> 2) + 4 * kh] = (int)(kmin[j] & 1023u);
  }

  // Epilogue (same-wave lgkmcnt ordering): x from LDS, emb gather from L2,
  // 1 KB contiguous out stores.
  float lp = 0.f;
#pragma unroll
  for (int g = 0; g < RPW / 4; ++g) {
    const int wrow = g * 4 + rig;
    const size_t r = rbase + wrow;
    const int bi = s_bi[wrow];
    float4 xv = *(const float4*)&s_x[wrow * LROW + chk * 4];
    float4 qv = ((const float4*)(emb + (size_t)bi * D))[chk];
    float dx = qv.x - xv.x, dy = qv.y - xv.y;
    float dz = qv.z - xv.z, dw = qv.w - xv.w;
    lp = fmaf(dx, dx, lp); lp = fmaf(dy, dy, lp);
    lp = fmaf(dz, dz, lp); lp = fmaf(dw, dw, lp);
    float4 ov;
    ov.x = xv.x + dx; ov.y = xv.y + dy;   // same rounding as x + sg(q-x)
    ov.z = xv.z + dz; ov.w = xv.w + dw;
    ((float4*)(out + r * D))[chk] = ov;
  }

#pragma unroll
  for (int o2 = 32; o2 > 0; o2 >>= 1) lp += __shfl_down(lp, o2, 64);
  if (lane == 0) partial[blockIdx.x] = lp;
}

// ---------------------------------------------------------------- loss -----
__global__ __launch_bounds__(256) void vq_loss_kernel(
    const float* __restrict__ partial, float* __restrict__ out) {
  __shared__ float wsum[4];
  int tid = threadIdx.x;
  float v = 0.f;
#pragma unroll
  for (int i = 0; i < NBLK / 256; ++i) v += partial[tid + i * 256];
#pragma unroll
  for (int off = 32; off > 0; off >>= 1) v += __shfl_down(v, off, 64);
  if ((tid & 63) == 0) wsum[tid >> 6] = v;
  __syncthreads();
  if (tid == 0) {
    float total = (wsum[0] + wsum[1]) + (wsum[2] + wsum[3]);
    out[(size_t)N_ROWS * D] = 1.25f * total / (float)((size_t)N_ROWS * D);
  }
}

// ------------------------------------------------------------- launch ------
extern "C" void kernel_launch(void* const* d_in, const int* in_sizes, int n_in,
                              void* d_out, int out_size, void* d_ws,
                              size_t ws_size, hipStream_t stream) {
  const float* x   = (const float*)d_in[0];   // [131072, 64] fp32
  const float* emb = (const float*)d_in[1];   // [1024, 64] fp32
  float* out = (float*)d_out;

  char* ws = (char*)d_ws;
  float* partial = (float*)ws;                 // 16 KB (NBLK floats)
  uint4* ebf     = (uint4*)(ws + 16384);       // 64 KB fp8 codebook

  vq_prep_kernel<<<16, 64, 0, stream>>>(emb, ebf);
  vq_main_kernel<<<NBLK, TPB, 0, stream>>>(x, ebf, emb, out, partial);
  vq_loss_kernel<<<1, 256, 0, stream>>>(partial, out);
}